// Round 19
// baseline (3540.869 us; speedup 1.0000x reference)
//
#include <hip/hip_runtime.h>
#include <hip/hip_fp16.h>
#include <cstdint>

#define B_SZ 4
#define T_SZ 512
#define D_SZ 768
#define H_SZ 768
#define G4   3072           // 4*H
#define V_SZ 50257
#define V_PAD 50304         // 393*128
#define M_SZ 2048           // T*B
#define FUSE_WGS 192        // 96 L0 blocks + 96 L1 blocks, 256 threads each
#define RWORDS 1536         // ring words per slot (2 fp16 h-values per word)

using half8 = __attribute__((ext_vector_type(8))) _Float16;
using f32x4 = __attribute__((ext_vector_type(4))) float;
typedef unsigned long long ull;

static __device__ __forceinline__ unsigned short f16bits(_Float16 x) {
  union { _Float16 f; unsigned short u; } cv; cv.f = x; return cv.u;
}
static __device__ __forceinline__ float f16val(unsigned short u) {
  union { unsigned short u; _Float16 f; } cv; cv.u = u; return (float)cv.f;
}

// ---------------- conversion kernels ----------------

__global__ void conv_A0(const float* __restrict__ reps, _Float16* __restrict__ A0) {
  int idx = blockIdx.x * blockDim.x + threadIdx.x;
  const int total = M_SZ * D_SZ;
  for (; idx < total; idx += gridDim.x * blockDim.x) {
    int k = idx % D_SZ, m = idx / D_SZ;
    int t = m >> 2, b = m & 3;
    A0[idx] = (_Float16)reps[(b * T_SZ + t) * D_SZ + k];
  }
}

__global__ void conv_cast(const float* __restrict__ src, _Float16* __restrict__ dst, int n) {
  int idx = blockIdx.x * blockDim.x + threadIdx.x;
  for (; idx < n; idx += gridDim.x * blockDim.x) dst[idx] = (_Float16)src[idx];
}

__global__ void conv_head(const float* __restrict__ w, _Float16* __restrict__ dst) {
  int idx = blockIdx.x * blockDim.x + threadIdx.x;
  const int total = V_PAD * H_SZ;
  for (; idx < total; idx += gridDim.x * blockDim.x) {
    int n = idx / H_SZ, k = idx % H_SZ;
    dst[idx] = (n < V_SZ) ? (_Float16)w[n * H_SZ + k] : (_Float16)0.f;
  }
}

// ---------------- f16 MFMA GEMM (r18 version, global_load_lds staging) ----------------

__global__ __launch_bounds__(256) void gemm_bt_f16(
    const _Float16* __restrict__ A, const _Float16* __restrict__ B,
    const float* __restrict__ bias, float* __restrict__ C,
    int M, int N, int K, int mode, int Nreal)
{
  __shared__ __align__(16) _Float16 As[128][32];
  __shared__ __align__(16) _Float16 Bs[128][32];
  const int t = threadIdx.x;
  const int lane = t & 63, w = t >> 6;
  const int wr = w >> 1, wc = w & 1;
  const int m0 = blockIdx.x * 128, n0 = blockIdx.y * 128;

  f32x4 acc[4][4] = {};

  const int srow = t >> 2;
  const int scol = (t & 3) * 8;

  const _Float16* ga0 = &A[(size_t)(m0 + srow) * K + scol];
  const _Float16* ga1 = &A[(size_t)(m0 + 64 + srow) * K + scol];
  const _Float16* gb0 = &B[(size_t)(n0 + srow) * K + scol];
  const _Float16* gb1 = &B[(size_t)(n0 + 64 + srow) * K + scol];
  _Float16* lA0 = &As[0][0] + w * 512;
  _Float16* lA1 = &As[64][0] + w * 512;
  _Float16* lB0 = &Bs[0][0] + w * 512;
  _Float16* lB1 = &Bs[64][0] + w * 512;

  for (int k0 = 0; k0 < K; k0 += 32) {
    __syncthreads();
    __builtin_amdgcn_global_load_lds(ga0 + k0, lA0, 16, 0, 0);
    __builtin_amdgcn_global_load_lds(ga1 + k0, lA1, 16, 0, 0);
    __builtin_amdgcn_global_load_lds(gb0 + k0, lB0, 16, 0, 0);
    __builtin_amdgcn_global_load_lds(gb1 + k0, lB1, 16, 0, 0);
    asm volatile("s_waitcnt vmcnt(0)" ::: "memory");
    __syncthreads();

    const int fr = lane & 15, k8 = (lane >> 4) * 8;
    half8 af[4], bf[4];
#pragma unroll
    for (int i = 0; i < 4; ++i) {
      af[i] = *(const half8*)&As[wr * 64 + i * 16 + fr][k8];
      bf[i] = *(const half8*)&Bs[wc * 64 + i * 16 + fr][k8];
    }
#pragma unroll
    for (int i = 0; i < 4; ++i)
#pragma unroll
      for (int j = 0; j < 4; ++j)
        acc[i][j] = __builtin_amdgcn_mfma_f32_16x16x32_f16(af[i], bf[j], acc[i][j], 0, 0, 0);
  }

  const int fr = lane & 15, rq = lane >> 4;
#pragma unroll
  for (int i = 0; i < 4; ++i) {
#pragma unroll
    for (int j = 0; j < 4; ++j) {
      int n = n0 + wc * 64 + j * 16 + fr;
      if (n >= Nreal) continue;
      float bv = bias[n];
#pragma unroll
      for (int r = 0; r < 4; ++r) {
        int m = m0 + wr * 64 + i * 16 + rq * 4 + r;
        float v = acc[i][j][r] + bv;
        if (mode == 0) {
          C[(size_t)m * N + n] = v;
        } else {
          int tt = m >> 2, bb = m & 3;
          C[(size_t)(bb * T_SZ + tt) * V_SZ + n] = v;
        }
      }
    }
  }
}

// ---------------- round-19 scan: r16 skeleton + fp16-pair exchange + merged combine ----------------
// r16 proven base (240 VGPR, no spill, ring-tag sync). Three changes:
// 1. Exchange word = [tag:u32 | 2xfp16]: ring slots are 1536 words (12KB);
//    word w = col*2 + b/2 holds (b even, b odd). Halves exchange traffic
//    AND staging regs (v[6] per buffer).
// 2. L1 gathers h0+h1 INTERLEAVED (6+6 words, one combined tag-poll):
//    merges the two serialized MALL round trips. Staging peak 24 regs = r16.
// 3. Merged activation+combine: t<32 reads 16 red[] partials, all 4
//    activations + LSTM combine with cstate IN REGISTER; sync3/actv/cst
//    deleted. Lanes with even b publish fp16 pairs (partner via shfl_xor 1).
// Numerics: only the RECURRENT exchange is fp16-quantized (head/h1hist path
// was already fp16 in all passing rounds; fp32 cstate carries the memory).
// Sync protocol unchanged (r13/r16-proven): store epoch e -> slot e&7 tag
// e+1; reader epoch x -> slot (x-1)&7 tag >= x; L0 back-pressure t0 e>=5
// polls hx1p word 0 of slot (e-5)&7 tag >= e-4 (lead < 8); L1 e=0 seeds
// slot 0 (16 words, tag 1, fp16 zeros). Rings memset 0 per launch.

__global__ __launch_bounds__(256) void lstm_fused(
    const float* __restrict__ xg0,    // (2048,3072) layer-0 input projections
    const float* __restrict__ Wih1,   // (3072,768) fp32 layer-1 input weights
    const float* __restrict__ Whh,    // (2,3072,768) fp32
    const float* __restrict__ bias,   // (2,3072) fp32
    ull* __restrict__ hx0p,           // [8][1536] packed ring, pre-zeroed
    ull* __restrict__ hx1p,           // [8][1536] packed ring, pre-zeroed
    _Float16* __restrict__ h1hist)    // (2048,768) fp16, row = t*4+b
{
  __shared__ __align__(16) float h0buf[G4];        // [k][b]
  __shared__ __align__(16) float h1buf[G4];        // [k][b] (L1 carry)
  __shared__ __align__(16) float red[4][8][4][4];  // [gate][c][q][b]

  const int t = threadIdx.x, lane = t & 63, wv = t >> 6;
  const bool L1 = blockIdx.x >= 96;
  const int lid = L1 ? (blockIdx.x - 96) : blockIdx.x;
  const int j0 = lid * 8;

  const float* WhhL = Whh + (L1 ? (size_t)G4 * H_SZ : 0);

  float wreg[8][12];
#pragma unroll
  for (int c = 0; c < 8; ++c)
#pragma unroll
    for (int kk = 0; kk < 12; ++kk)
      wreg[c][kk] = WhhL[(size_t)(wv * H_SZ + j0 + c) * H_SZ + kk * 64 + lane];

  float wreg2[8][12];
  if (L1) {
#pragma unroll
    for (int c = 0; c < 8; ++c)
#pragma unroll
      for (int kk = 0; kk < 12; ++kk)
        wreg2[c][kk] = Wih1[(size_t)(wv * H_SZ + j0 + c) * H_SZ + kk * 64 + lane];
  }

  // combine-thread (t<32) state: c = t>>2, b = t&3
  const int cc = t >> 2, cb = t & 3;
  float cstate = 0.f;
  float breg4[4] = {0.f, 0.f, 0.f, 0.f};
  if (L1 && t < 32) {
#pragma unroll
    for (int g = 0; g < 4; ++g) breg4[g] = bias[G4 + g * H_SZ + j0 + cc];
  }

  const int elim = L1 ? 513 : 512;
  for (int e = 0; e < elim; ++e) {
    if (L1 && e == 0) {
      // seed h1[-1] = 0 (fp16 zeros) with tag 1: 16 words for own 8 cols
      if (t < 16)
        __hip_atomic_store(&hx1p[(size_t)(j0 * 2 + t)], (ull)1u << 32,
                           __ATOMIC_RELAXED, __HIP_MEMORY_SCOPE_AGENT);
      continue;  // block-uniform: no LDS touched, barriers legally skipped
    }

    // L0 combine-thread xg prefetch (4 gates) before polls
    float xg4[4] = {0.f, 0.f, 0.f, 0.f};
    if (!L1 && t < 32) {
      const float* xp = xg0 + (size_t)((e << 2) + cb) * G4 + j0 + cc;
#pragma unroll
      for (int g = 0; g < 4; ++g) xg4[g] = xp[g * H_SZ];
    }

    // L0 back-pressure (t0, e>=5): one h1 word, slot (e-5)&7, tag >= e-4
    if (!L1 && t == 0 && e >= 5) {
      const ull* bp = hx1p + (size_t)((e - 5) & 7) * RWORDS;
      while ((unsigned)(__hip_atomic_load(bp, __ATOMIC_RELAXED, __HIP_MEMORY_SCOPE_AGENT) >> 32)
             < (unsigned)(e - 4))
        __builtin_amdgcn_s_sleep(1);
    }

    const unsigned need = (unsigned)e;
    const size_t slot = (size_t)((e + 7) & 7) * RWORDS;

    // interleaved tag-gated gather: 6 h0 words (+6 h1 words for L1), one poll
    ull v0[6], v1[6];
    {
      const ull* s0 = hx0p + slot;
      const ull* s1 = hx1p + slot;
#pragma unroll
      for (int i = 0; i < 6; ++i)
        v0[i] = __hip_atomic_load(&s0[t + i * 256], __ATOMIC_RELAXED, __HIP_MEMORY_SCOPE_AGENT);
      if (L1) {
#pragma unroll
        for (int i = 0; i < 6; ++i)
          v1[i] = __hip_atomic_load(&s1[t + i * 256], __ATOMIC_RELAXED, __HIP_MEMORY_SCOPE_AGENT);
      }
      for (;;) {
        bool stale = false;
#pragma unroll
        for (int i = 0; i < 6; ++i) stale |= ((unsigned)(v0[i] >> 32) < need);
        if (L1) {
#pragma unroll
          for (int i = 0; i < 6; ++i) stale |= ((unsigned)(v1[i] >> 32) < need);
        }
        if (!stale) break;
        __builtin_amdgcn_s_sleep(1);
#pragma unroll
        for (int i = 0; i < 6; ++i)
          if ((unsigned)(v0[i] >> 32) < need)
            v0[i] = __hip_atomic_load(&s0[t + i * 256], __ATOMIC_RELAXED, __HIP_MEMORY_SCOPE_AGENT);
        if (L1) {
#pragma unroll
          for (int i = 0; i < 6; ++i)
            if ((unsigned)(v1[i] >> 32) < need)
              v1[i] = __hip_atomic_load(&s1[t + i * 256], __ATOMIC_RELAXED, __HIP_MEMORY_SCOPE_AGENT);
        }
      }
      // unpack fp16 pairs to fp32 LDS (word w -> hbuf[2w], hbuf[2w+1])
#pragma unroll
      for (int i = 0; i < 6; ++i) {
        int w2 = (t + i * 256) * 2;
        unsigned pl = (unsigned)v0[i];
        float2 f; f.x = f16val((unsigned short)(pl & 0xffff));
        f.y = f16val((unsigned short)(pl >> 16));
        *(float2*)&h0buf[w2] = f;
      }
      if (L1) {
#pragma unroll
        for (int i = 0; i < 6; ++i) {
          int w2 = (t + i * 256) * 2;
          unsigned pl = (unsigned)v1[i];
          float2 f; f.x = f16val((unsigned short)(pl & 0xffff));
          f.y = f16val((unsigned short)(pl >> 16));
          *(float2*)&h1buf[w2] = f;
        }
      }
    }
    __syncthreads();   // sync 1

    // matvec + butterfly (r16 shape)
    float4 acc[8];
#pragma unroll
    for (int c = 0; c < 8; ++c) acc[c] = make_float4(0.f, 0.f, 0.f, 0.f);

    if (!L1) {
#pragma unroll
      for (int kk = 0; kk < 12; ++kk) {
        float4 h4 = *(const float4*)&h0buf[(kk * 64 + lane) * 4];
#pragma unroll
        for (int c = 0; c < 8; ++c) {
          float wf = wreg[c][kk];
          acc[c].x = fmaf(wf, h4.x, acc[c].x);
          acc[c].y = fmaf(wf, h4.y, acc[c].y);
          acc[c].z = fmaf(wf, h4.z, acc[c].z);
          acc[c].w = fmaf(wf, h4.w, acc[c].w);
        }
      }
    } else {
#pragma unroll
      for (int kk = 0; kk < 12; ++kk) {
        float4 x4 = *(const float4*)&h0buf[(kk * 64 + lane) * 4];
        float4 h4 = *(const float4*)&h1buf[(kk * 64 + lane) * 4];
#pragma unroll
        for (int c = 0; c < 8; ++c) {
          float wx = wreg2[c][kk], wh = wreg[c][kk];
          acc[c].x = fmaf(wx, x4.x, fmaf(wh, h4.x, acc[c].x));
          acc[c].y = fmaf(wx, x4.y, fmaf(wh, h4.y, acc[c].y));
          acc[c].z = fmaf(wx, x4.z, fmaf(wh, h4.z, acc[c].z));
          acc[c].w = fmaf(wx, x4.w, fmaf(wh, h4.w, acc[c].w));
        }
      }
    }

#pragma unroll
    for (int mask = 1; mask <= 8; mask <<= 1) {
#pragma unroll
      for (int c = 0; c < 8; ++c) {
        acc[c].x += __shfl_xor(acc[c].x, mask, 64);
        acc[c].y += __shfl_xor(acc[c].y, mask, 64);
        acc[c].z += __shfl_xor(acc[c].z, mask, 64);
        acc[c].w += __shfl_xor(acc[c].w, mask, 64);
      }
    }
    if ((lane & 15) == 0) {
      int q = lane >> 4;
#pragma unroll
      for (int c = 0; c < 8; ++c) *(float4*)&red[wv][c][q][0] = acc[c];
    }
    __syncthreads();   // sync 2

    // merged activation + combine + packed fp16-pair store (t<32)
    if (t < 32) {
      float s[4];
#pragma unroll
      for (int g = 0; g < 4; ++g)
        s[g] = red[g][cc][0][cb] + red[g][cc][1][cb] + red[g][cc][2][cb] + red[g][cc][3][cb]
             + (L1 ? breg4[g] : xg4[g]);
      float iv = 1.f / (1.f + expf(-s[0]));
      float fv = 1.f / (1.f + expf(-s[1]));
      float gv = tanhf(s[2]);
      float ov = 1.f / (1.f + expf(-s[3]));
      cstate = fv * cstate + iv * gv;
      float hn = ov * tanhf(cstate);
      float hp = __shfl_xor(hn, 1, 64);       // partner b^1 (both lanes active)
      if ((cb & 1) == 0) {
        unsigned pl = (unsigned)f16bits((_Float16)hn)
                    | ((unsigned)f16bits((_Float16)hp) << 16);
        ull p = ((ull)(unsigned)(e + 1) << 32) | (ull)pl;
        ull* dst = (L1 ? hx1p : hx0p) + (size_t)(e & 7) * RWORDS;
        __hip_atomic_store(&dst[(j0 + cc) * 2 + (cb >> 1)], p,
                           __ATOMIC_RELAXED, __HIP_MEMORY_SCOPE_AGENT);
      }
      if (L1)
        h1hist[(size_t)(((e - 1) << 2) + cb) * H_SZ + j0 + cc] = (_Float16)hn;
    }
    // no sync3 needed: t>=32 may run ahead into next gather, but it only
    // overwrites h0buf/h1buf (matvec reads completed before sync2) and its
    // red[] writes wait at next sync1+matvec, after t<32 passed sync1 too.
  }
}

// ---------------- launcher ----------------

extern "C" void kernel_launch(void* const* d_in, const int* in_sizes, int n_in,
                              void* d_out, int out_size, void* d_ws, size_t ws_size,
                              hipStream_t stream) {
  const float* reps   = (const float*)d_in[0];
  const float* W_ih   = (const float*)d_in[1];
  const float* W_hh   = (const float*)d_in[2];
  const float* bias   = (const float*)d_in[3];
  const float* head_w = (const float*)d_in[4];
  const float* head_b = (const float*)d_in[5];
  float* out = (float*)d_out;

  char* ws = (char*)d_ws;
  _Float16* A0h    = (_Float16*)(ws + 0);            //  3,145,728 B
  _Float16* Wih_h  = (_Float16*)(ws + 3145728);      //  4,718,592 B (layer 0 only)
  _Float16* Whead  = (_Float16*)(ws + 12582912);     // 77,266,944 B (padded)
  float*    xg0    = (float*)   (ws + 89849856);     // 25,165,824 B
  _Float16* h1hist = (_Float16*)(ws + 115015680);    //  3,145,728 B
  ull*      hx0p   = (ull*)     (ws + 118161408);    //     98,304 B ([8][1536] packed)
  ull*      hx1p   = (ull*)     (ws + 118259712);    //     98,304 B ([8][1536] packed)

  // conversions
  hipLaunchKernelGGL(conv_A0,   dim3(1024), dim3(256), 0, stream, reps, A0h);
  hipLaunchKernelGGL(conv_cast, dim3(1024), dim3(256), 0, stream, W_ih, Wih_h, G4 * D_SZ);
  hipLaunchKernelGGL(conv_head, dim3(4096), dim3(256), 0, stream, head_w, Whead);

  // xg0 = A0 * Wih0^T + b0
  hipLaunchKernelGGL(gemm_bt_f16, dim3(16, 24), dim3(256), 0, stream,
                     A0h, Wih_h, bias, xg0, M_SZ, G4, H_SZ, 0, G4);

  // ring-tag pipelined 2-layer scan (192 blocks x 256 threads)
  hipMemsetAsync(hx0p, 0, 196608, stream);  // hx0p + hx1p contiguous
  hipLaunchKernelGGL(lstm_fused, dim3(FUSE_WGS), dim3(256), 0, stream,
                     xg0, W_ih + (size_t)G4 * D_SZ, W_hh, bias,
                     hx0p, hx1p, h1hist);

  // logits = h1 * head_w^T + head_b  (padded N, permuted store into (B,T,V))
  hipLaunchKernelGGL(gemm_bt_f16, dim3(16, 393), dim3(256), 0, stream,
                     h1hist, Whead, head_b, out, M_SZ, V_PAD, H_SZ, 1, V_SZ);
}